// Round 9
// baseline (217.592 us; speedup 1.0000x reference)
//
#include <hip/hip_runtime.h>

// HistLoss: per-channel histogram matching + MSE loss.
// C=64, H=W=512, HW=262144, NBINS=256, STRENGTH=100.
//
// R18: fix the two parallelism-starved kernels. Evidence (R17):
// k_p1h (pass1+Jhist fused) < 44us (top-5 cutoff) -- fusion kept;
// k_closs 44.5us @ 22MB, 490GB/s, occ 37% (grid 1024 = 4blk/CU cap),
// VGPR 28 (low-MLP pc loop); k_prep 256 blk = 8 waves/CU (latency-
// starved J read). Cross-round fit: fixed ~75us graph/dispatch gap
// independent of kernel count (R12: 111 kernel-us + 77; R17: 131 + 76)
// => minimize KERNEL-TIME SUM. In-kernel cross-block sync remains
// banned (R14/R15/R16: ~100+us stall each).
//  k_prep: 576 blk x 512thr (18 waves/CU): blk<64 byte-pack masks
//    (R10-proven); else (s in [0,64) x octet g): mask nibbles in regs
//    reused across 8 channels' J minmax -> mnp/mxp[c][64].
//  k_p1h: UNCHANGED from R17 except minmax reduce reads 64 partials
//    (1 wave shfl) and qtot 32 groups of 256 buckets (shfl-16).
//  k_closs: 32 blk/ch x 256 thr (2048 blk, 32 waves/CU), 1 bucket/thr,
//    colsum-parallel sh_base, 4-way unrolled pc accumulation.
// All minmax/integer regroupings exact; cumsum/remap math verbatim
// (absmax 0.0 R3-R17; threshold 2.9e-6).

#define CN    64
#define HWN   262144
#define NB    256
#define NBUK  8192
#define NBLK  16                  // k_p1h slices per channel
#define BPIX  (HWN/NBLK)          // 16384 px per k_p1h block
#define PT    512
#define MMS   64                  // minmax slices per channel
#define MMPIX (HWN/MMS)           // 4096 px
#define CLB   32                  // k_closs blocks per channel
#define CBUK  (NBUK/CLB)          // 256 buckets per k_closs block
#define FXS2  268435456.0f        // 2^28 fixed-point scale for sum(v-center)
#define FXSI2 (1.0/268435456.0)

// blocks 0-63: pack masks to bits (byte-wise, R10-proven layout).
// blocks 64-575: (slice s, channel-octet g) masked J minmax partials.
__global__ __launch_bounds__(512) void k_prep(
    const float* __restrict__ J, const int* __restrict__ mI,
    const int* __restrict__ mJ, unsigned char* __restrict__ bI,
    unsigned char* __restrict__ bJ, unsigned* __restrict__ mnp,
    unsigned* __restrict__ mxp, double* __restrict__ lossacc,
    unsigned* __restrict__ donecnt)
{
  const int bx = blockIdx.x, tid = threadIdx.x;
  __shared__ unsigned smn[8][8], smx[8][8];
  if(bx < 64){
    const int t = bx*512 + tid;                      // 32768 threads x 8 px
    const int4* a = (const int4*)mI + 2*t;
    int4 x0 = a[0], x1 = a[1];
    unsigned b = (unsigned)((x0.x>0)|((x0.y>0)<<1)|((x0.z>0)<<2)|((x0.w>0)<<3)
               |((x1.x>0)<<4)|((x1.y>0)<<5)|((x1.z>0)<<6)|((x1.w>0)<<7));
    const int4* cm = (const int4*)mJ + 2*t;
    int4 y0 = cm[0], y1 = cm[1];
    unsigned d = (unsigned)((y0.x>0)|((y0.y>0)<<1)|((y0.z>0)<<2)|((y0.w>0)<<3)
               |((y1.x>0)<<4)|((y1.y>0)<<5)|((y1.z>0)<<6)|((y1.w>0)<<7));
    bI[t] = (unsigned char)b;
    bJ[t] = (unsigned char)d;
    if(bx == 0 && tid == 0){ *lossacc = 0.0; *donecnt = 0u; }
    return;
  }
  const int m = bx - 64, s = m >> 3, g = m & 7;      // slice, channel-octet
  const int wid = tid >> 6, lane = tid & 63;
  const int4* mj4 = (const int4*)mJ + s*(MMPIX/4);   // mask nibbles, in regs,
  int4 y0 = mj4[tid], y1 = mj4[512 + tid];           // reused for 8 channels
  unsigned b40 = (unsigned)((y0.x>0)|((y0.y>0)<<1)|((y0.z>0)<<2)|((y0.w>0)<<3));
  unsigned b41 = (unsigned)((y1.x>0)|((y1.y>0)<<1)|((y1.z>0)<<2)|((y1.w>0)<<3));
  #pragma unroll
  for(int ch = 0; ch < 8; ch++){
    const int c = g*8 + ch;
    const float4* Jc = (const float4*)(J + (size_t)c*HWN + (size_t)s*MMPIX);
    float4 v0 = Jc[tid], v1 = Jc[512 + tid];
    unsigned mn = 0x7F800000u, mx = 0u;              // J in [0,1): uint-monotone
    if(b40&1u){unsigned u=__float_as_uint(v0.x); mn=min(mn,u); mx=max(mx,u);}
    if(b40&2u){unsigned u=__float_as_uint(v0.y); mn=min(mn,u); mx=max(mx,u);}
    if(b40&4u){unsigned u=__float_as_uint(v0.z); mn=min(mn,u); mx=max(mx,u);}
    if(b40&8u){unsigned u=__float_as_uint(v0.w); mn=min(mn,u); mx=max(mx,u);}
    if(b41&1u){unsigned u=__float_as_uint(v1.x); mn=min(mn,u); mx=max(mx,u);}
    if(b41&2u){unsigned u=__float_as_uint(v1.y); mn=min(mn,u); mx=max(mx,u);}
    if(b41&4u){unsigned u=__float_as_uint(v1.z); mn=min(mn,u); mx=max(mx,u);}
    if(b41&8u){unsigned u=__float_as_uint(v1.w); mn=min(mn,u); mx=max(mx,u);}
    for(int o = 32; o > 0; o >>= 1){
      mn = min(mn, (unsigned)__shfl_down(mn, o, 64));
      mx = max(mx, (unsigned)__shfl_down(mx, o, 64));
    }
    if(lane == 0){ smn[wid][ch] = mn; smx[wid][ch] = mx; }
  }
  __syncthreads();
  if(tid < 8){                                       // ch = tid
    unsigned mn = 0x7F800000u, mx = 0u;
    for(int w = 0; w < 8; w++){ mn = min(mn, smn[w][tid]); mx = max(mx, smx[w][tid]); }
    mnp[(g*8 + tid)*MMS + s] = mn;
    mxp[(g*8 + tid)*MMS + s] = mx;
  }
}

__device__ __forceinline__ void px_i(float v, float& qacc, unsigned& ci,
                                     unsigned* buk){
  int k = (int)(v * (float)NBUK);                    // pow2 scale: exact, monotone
  if(k > NBUK-1) k = NBUK-1;
  float dv = v - ((float)k + 0.5f) * (1.0f/(float)NBUK);
  int fx = (int)rintf(dv * FXS2);                    // |fx| <= 16384
  atomicAdd(&buk[k], ((unsigned)fx << 12) + 1u);
  qacc += dv*dv;
  ci++;
}

// pass1 + J-histogram fused (minmax known from k_prep via boundary).
__global__ __launch_bounds__(PT, 2) void k_p1h(
    const float* __restrict__ I, const float* __restrict__ J,
    const unsigned* __restrict__ bIw, const unsigned* __restrict__ bJw,
    const unsigned* __restrict__ mnp, const unsigned* __restrict__ mxp,
    unsigned* __restrict__ pc, unsigned* __restrict__ qtot,
    unsigned* __restrict__ hisPart, unsigned* __restrict__ cp,
    double* __restrict__ qp)
{
  const int c = blockIdx.y, q = blockIdx.x, tid = threadIdx.x;
  const int bid = c*NBLK + q;
  const int wid = tid >> 6, lane = tid & 63;
  __shared__ unsigned buk[NBUK];                    // packed (fx<<12)+count
  __shared__ unsigned smbI[BPIX/32], smbJ[BPIX/32]; // 512 words each
  __shared__ unsigned h2[2][NB];                    // J-hist sub-hists
  __shared__ double   dred[PT/64];
  __shared__ unsigned uci[PT/64], ucj[PT/64];
  __shared__ float sh_mn, sh_den;
  for(int i = tid; i < NBUK; i += PT) buk[i] = 0u;
  smbI[tid] = bIw[q*512 + tid];                     // PT == 512 words
  smbJ[tid] = bJw[q*512 + tid];
  if(tid < NB){ h2[0][tid] = 0u; h2[1][tid] = 0u; }
  if(tid < MMS){                                    // channel minmax, 1 wave
    unsigned mn = mnp[c*MMS + tid];
    unsigned mx = mxp[c*MMS + tid];
    for(int o = 32; o > 0; o >>= 1){
      mn = min(mn, (unsigned)__shfl_down(mn, o, 64));
      mx = max(mx, (unsigned)__shfl_down(mx, o, 64));
    }
    if(tid == 0){
      float mnv = __uint_as_float(mn);
      sh_mn  = mnv;
      sh_den = fmaxf((__uint_as_float(mx) - mnv) / (float)NB, 1e-12f);
    }
  }
  __syncthreads();

  const float4* Ic = (const float4*)(I + (size_t)c*HWN + (size_t)q*BPIX);
  const float4* Jc = (const float4*)(J + (size_t)c*HWN + (size_t)q*BPIX);
  const float mnv = sh_mn, den = sh_den;
  float qacc = 0.0f;
  unsigned ci = 0, cj = 0;
  const int nsh = (tid & 7) * 4;
  const int bw  = tid >> 3;
  unsigned* hh = h2[wid & 1];

  float4 pi[2], pj[2];                              // 2-deep reg pipeline (R12)
  pi[0] = Ic[tid]; pj[0] = Jc[tid];
  #pragma unroll
  for(int g = 0; g < 8; g++){
    const int cur = g & 1, nxt = cur ^ 1;
    if(g < 7){ pi[nxt] = Ic[(g+1)*PT + tid]; pj[nxt] = Jc[(g+1)*PT + tid]; }
    const unsigned bitsI = (smbI[g*64 + bw] >> nsh) & 0xFu;
    const unsigned bitsJ = (smbJ[g*64 + bw] >> nsh) & 0xFu;
    float4 vi = pi[cur], vj = pj[cur];
    if(bitsI & 1u) px_i(vi.x, qacc, ci, buk);
    if(bitsI & 2u) px_i(vi.y, qacc, ci, buk);
    if(bitsI & 4u) px_i(vi.z, qacc, ci, buk);
    if(bitsI & 8u) px_i(vi.w, qacc, ci, buk);
    if(bitsJ & 1u){ float bf = floorf((vj.x - mnv)/den);  // ref rounding
      bf = fminf(fmaxf(bf,0.0f),255.0f); atomicAdd(&hh[(int)bf],1u); cj++; }
    if(bitsJ & 2u){ float bf = floorf((vj.y - mnv)/den);
      bf = fminf(fmaxf(bf,0.0f),255.0f); atomicAdd(&hh[(int)bf],1u); cj++; }
    if(bitsJ & 4u){ float bf = floorf((vj.z - mnv)/den);
      bf = fminf(fmaxf(bf,0.0f),255.0f); atomicAdd(&hh[(int)bf],1u); cj++; }
    if(bitsJ & 8u){ float bf = floorf((vj.w - mnv)/den);
      bf = fminf(fmaxf(bf,0.0f),255.0f); atomicAdd(&hh[(int)bf],1u); cj++; }
  }
  __syncthreads();                                   // LDS atomics complete
  { unsigned* pcb = pc + (size_t)bid * NBUK;
    for(int i = tid; i < NBUK; i += PT) pcb[i] = buk[i]; }
  if(tid < NB) hisPart[(size_t)bid*NB + tid] = h2[0][tid] + h2[1][tid];

  // qtot: 32 groups of 256 buckets; 16-thread shfl reduce (integer-exact)
  { unsigned csum = 0;
    #pragma unroll
    for(int j = 0; j < 16; j++) csum += buk[tid*16 + j] & 0xFFFu;
    csum += __shfl_down(csum, 8, 64);
    csum += __shfl_down(csum, 4, 64);
    csum += __shfl_down(csum, 2, 64);
    csum += __shfl_down(csum, 1, 64);
    if((tid & 15) == 0) qtot[bid*32 + (tid >> 4)] = csum;
  }

  double qd = (double)qacc;
  for(int o = 32; o > 0; o >>= 1){
    qd += __shfl_down(qd, o, 64);
    ci += __shfl_down(ci, o, 64);
    cj += __shfl_down(cj, o, 64);
  }
  if(lane == 0){ dred[wid] = qd; uci[wid] = ci; ucj[wid] = cj; }
  __syncthreads();
  if(tid == 0){
    double t = 0.0; unsigned aci = 0, acj = 0;
    for(int w = 0; w < PT/64; w++){ t += dred[w]; aci += uci[w]; acj += ucj[w]; }
    qp[bid] = t;
    if(c == 0){ cp[2*q] = aci; cp[2*q+1] = acj; }
  }
}

__global__ __launch_bounds__(256) void k_closs(
    const unsigned* __restrict__ pc, const unsigned* __restrict__ qtot,
    const unsigned* __restrict__ hisPart,
    const unsigned* __restrict__ mnp, const unsigned* __restrict__ mxp,
    const unsigned* __restrict__ cp, const double* __restrict__ qp,
    double* __restrict__ lossacc, unsigned* __restrict__ donecnt,
    float* __restrict__ out)
{
  const int c = blockIdx.y, qt = blockIdx.x, tid = threadIdx.x; // qt in [0,32)
  const int wid = tid >> 6, lane = tid & 63;
  __shared__ unsigned hsum[NB], qsh[NBLK*32];
  __shared__ float cs[NB], hs[NB];
  __shared__ unsigned colsum[32], wsum[4];
  __shared__ double red2[4];
  __shared__ float sh_mn, sh_st;
  __shared__ unsigned sh_base;

  if(tid < MMS){                                     // channel minmax, 1 wave
    unsigned mn = mnp[c*MMS + tid];
    unsigned mx = mxp[c*MMS + tid];
    for(int o = 32; o > 0; o >>= 1){
      mn = min(mn, (unsigned)__shfl_down(mn, o, 64));
      mx = max(mx, (unsigned)__shfl_down(mx, o, 64));
    }
    if(tid == 0){
      float mnv = __uint_as_float(mn);
      sh_mn = mnv;
      sh_st = (__uint_as_float(mx) - mnv) / (float)NB; // remap step (unclamped)
    }
  }
  { unsigned hr = 0u;                                // hisPart reduce, all 256
    #pragma unroll
    for(int xb = 0; xb < NBLK; xb++) hr += hisPart[(size_t)(c*NBLK + xb)*NB + tid];
    hsum[tid] = hr; }
  qsh[tid]       = qtot[c*NBLK*32 + tid];
  qsh[tid + 256] = qtot[c*NBLK*32 + 256 + tid];
  __syncthreads();
  if(tid < 32){                                      // per-group column sums
    unsigned csm = 0;
    #pragma unroll
    for(int sl = 0; sl < NBLK; sl++) csm += qsh[sl*32 + tid];
    colsum[tid] = csm;
  }
  __syncthreads();
  if(tid == 0){
    unsigned ciw = 0, cjw = 0;
    for(int qi = 0; qi < NBLK; qi++){ ciw += cp[2*qi]; cjw += cp[2*qi+1]; }
    float ratio = (float)ciw / (float)cjw;           // nI/nJ in f32, as in ref
    float cum = 0.0f;
    for(int b = 0; b < NB; b++){
      float hh = (float)hsum[b] * ratio;
      hs[b] = hh;
      cum += hh;                                     // sequential f32 == ref rounding
      cs[b] = cum;
    }
    unsigned base = 0;
    for(int g2 = 0; g2 < qt; g2++) base += colsum[g2];
    sh_base = base;
  }
  __syncthreads();

  // 1 bucket/thread (b = qt*CBUK + tid); pc plain loads, 4-way accumulators
  unsigned kk0=0, kk1=0, kk2=0, kk3=0;
  long long ss0=0, ss1=0, ss2=0, ss3=0;
  #pragma unroll
  for(int sl = 0; sl < NBLK; sl += 4){
    unsigned w0 = pc[(size_t)(c*NBLK + sl    )*NBUK + qt*CBUK + tid];
    unsigned w1 = pc[(size_t)(c*NBLK + sl + 1)*NBUK + qt*CBUK + tid];
    unsigned w2 = pc[(size_t)(c*NBLK + sl + 2)*NBUK + qt*CBUK + tid];
    unsigned w3 = pc[(size_t)(c*NBLK + sl + 3)*NBUK + qt*CBUK + tid];
    kk0 += w0 & 0xFFFu;  ss0 += (int)w0 >> 12;
    kk1 += w1 & 0xFFFu;  ss1 += (int)w1 >> 12;
    kk2 += w2 & 0xFFFu;  ss2 += (int)w2 >> 12;
    kk3 += w3 & 0xFFFu;  ss3 += (int)w3 >> 12;
  }
  unsigned  kk = kk0 + kk1 + kk2 + kk3;              // integer-exact
  long long ss = ss0 + ss1 + ss2 + ss3;
  unsigned v = kk;                                   // wave inclusive scan
  for(int o = 1; o < 64; o <<= 1){
    unsigned t = __shfl_up(v, o, 64);
    if(lane >= o) v += t;
  }
  if(lane == 63) wsum[wid] = v;
  __syncthreads();
  unsigned wbase = 0;
  for(int w = 0; w < wid; w++) wbase += wsum[w];
  unsigned texcl = sh_base + wbase + (v - kk);

  float  mnvf = sh_mn, stepf = sh_st;
  double mnvd = (double)mnvf, stepd = (double)stepf;

  float rf0 = (float)(texcl + 1u);                   // left-search start bin
  int lo = 0, hi = NB;
  while(lo < hi){ int mid = (lo + hi) >> 1; if(cs[mid] < rf0) lo = mid + 1; else hi = mid; }
  int bin = (lo > NB-1) ? NB-1 : lo;

  double acc = 0.0;
  if(kk){
    unsigned ra = texcl + 1u, rb = texcl + kk;
    double sval = 0.0;
    while(ra <= rb){
      while(bin < NB-1 && cs[bin] < (float)ra) bin++;
      float csb = cs[bin], hsb = hs[bin];
      unsigned re = (bin == NB-1) ? rb : min(rb, (unsigned)floorf(csb));
      double lovd = (double)csb - (double)hsb;
      double den2 = fmax((double)hsb, 1e-12);
      double ra_d = (double)ra, re_d = (double)re, nn = (double)(re - ra + 1u);
      double rta = (ra_d - lovd)/den2, rtb = (re_d - lovd)/den2;
      if(hsb > 0.0f && rta >= 0.0 && rtb <= 1.0){
        double sumr = 0.5*(ra_d + re_d)*nn;          // arithmetic series of ranks
        sval += nn*(mnvd + (double)bin*stepd) + stepd*(sumr - nn*lovd)/den2;
      } else {                                       // exact per-rank f32 fallback
        for(unsigned rr = ra; rr <= re; rr++){
          float rf = (float)rr;
          float lov = csb - hsb;
          float rt = (rf - lov) / fmaxf(hsb, 1e-12f);
          rt = fminf(fmaxf(rt, 0.0f), 1.0f);
          sval += (double)(mnvf + ((float)bin + rt)*stepf);
        }
      }
      ra = re + 1u;
    }
    double kb   = (double)kk;
    double cb   = ((double)(qt*CBUK + tid) + 0.5) * (1.0/(double)NBUK);
    double vbar = sval/kb - cb;                      // mean(val) - bucket center
    double S    = (double)ss * FXSI2;                // sum(v - center)
    acc = kb*vbar*vbar - 2.0*vbar*S;
  }
  if(qt == 0 && tid == 0){                           // Q_c once per channel
    double qsum = 0.0;
    for(int qi = 0; qi < NBLK; qi++) qsum += qp[c*NBLK + qi];
    acc += qsum;
  }
  for(int o = 32; o > 0; o >>= 1) acc += __shfl_down(acc, o, 64);
  if(lane == 0) red2[wid] = acc;
  __syncthreads();
  if(tid == 0){
    double t = 0.0;
    for(int w = 0; w < 4; w++) t += red2[w];
    atomicAdd(lossacc, t);
    __threadfence();
    unsigned old = atomicAdd(donecnt, 1u);
    if(old == (unsigned)(CN*CLB - 1)){               // last block finalizes
      double tot = atomicAdd(lossacc, 0.0);          // coherent read
      out[0] = (float)(tot * (100.0 / (double)((size_t)CN * HWN)));
    }
  }
}

extern "C" void kernel_launch(void* const* d_in, const int* in_sizes, int n_in,
                              void* d_out, int out_size, void* d_ws, size_t ws_size,
                              hipStream_t stream){
  const float* I  = (const float*)d_in[0];
  const float* J  = (const float*)d_in[1];
  const int*   mI = (const int*)d_in[2];
  const int*   mJ = (const int*)d_in[3];
  float* out = (float*)d_out;

  char* base = (char*)d_ws;
  size_t pcB = (size_t)CN * NBLK * NBUK * sizeof(unsigned);      // 32 MB
  unsigned* pc      = (unsigned*)base;
  char* p = base + pcB;
  double*   qp      = (double*)p;   p += (size_t)CN*NBLK*sizeof(double);
  double*   lossacc = (double*)p;   p += sizeof(double);
  unsigned* hisPart = (unsigned*)p; p += (size_t)CN*NBLK*NB*sizeof(unsigned);
  unsigned* qtot    = (unsigned*)p; p += (size_t)CN*NBLK*32*sizeof(unsigned);
  unsigned* mnp     = (unsigned*)p; p += (size_t)CN*MMS*sizeof(unsigned);
  unsigned* mxp     = (unsigned*)p; p += (size_t)CN*MMS*sizeof(unsigned);
  unsigned* cp      = (unsigned*)p; p += 2*NBLK*sizeof(unsigned);
  unsigned* donecnt = (unsigned*)p; p += sizeof(unsigned);
  size_t off = (size_t)(p - base); off = (off + 15) & ~(size_t)15;
  unsigned char* bIb = (unsigned char*)(base + off);             // 32 KB bits
  unsigned char* bJb = bIb + HWN/8;                              // 32 KB bits

  k_prep<<<576, 512, 0, stream>>>(J, mI, mJ, bIb, bJb, mnp, mxp,
                                  lossacc, donecnt);
  k_p1h<<<dim3(NBLK, CN), PT, 0, stream>>>(I, J, (const unsigned*)bIb,
                                           (const unsigned*)bJb, mnp, mxp,
                                           pc, qtot, hisPart, cp, qp);
  k_closs<<<dim3(CLB, CN), 256, 0, stream>>>(pc, qtot, hisPart, mnp, mxp,
                                             cp, qp, lossacc, donecnt, out);
}

// Round 10
// 186.236 us; speedup vs baseline: 1.1684x; 1.1684x over previous
//
#include <hip/hip_runtime.h>

// HistLoss: per-channel histogram matching + MSE loss.
// C=64, H=W=512, HW=262144, NBINS=256, STRENGTH=100.
//
// R19: hoist k_closs's replicated per-channel preamble into k_tab.
// Evidence (R18): k_closs 68.7us @ 22MB, occ 33%, VALU 12% -- each of
// the 2048 blocks redid the hisPart reduce + qtot staging + minmax +
// 256-iter SERIAL f32 cumsum (tid0 dependent chain, other waves
// barrier-blocked). Doubling blocks/channel doubled preamble => slower.
// Cross-round fit: inter-kernel gap is FIXED ~75-80us independent of
// kernel count (R12 4k / R17 3k / R18 3k all = sum + ~77) => a ~5us
// 4th kernel that deletes ~50us of replicated preamble is a net win.
//  k_prep:  UNCHANGED (R18): pack mask bits + J minmax partials.
//  k_p1h:   UNCHANGED (R18, <44us): pass1 + fused J-histogram.
//  k_tab:   NEW, 64 blk x 256thr: per-channel hisPart reduce, qtot
//           colsum + exclusive prefix colpre[32], minmax, ratio,
//           serial f32 cumsum ONCE (ref rounding) -> cs/hs tables.
//  k_closs: 16 blk/ch x 512thr, 1 bucket/thr: load 1KB tables +
//           colpre base, 4-way pc reduce, wave scan, remap verbatim.
// All boundary-crossing values are ints or f32 bit-copies; cumsum
// order unchanged (absmax 0.0 R3-R18; threshold 2.9e-6).

#define CN    64
#define HWN   262144
#define NB    256
#define NBUK  8192
#define NBLK  16                  // k_p1h slices per channel
#define BPIX  (HWN/NBLK)          // 16384 px per k_p1h block
#define PT    512
#define MMS   64                  // minmax slices per channel
#define MMPIX (HWN/MMS)           // 4096 px
#define CLB   16                  // k_closs blocks per channel
#define CBUK  (NBUK/CLB)          // 512 buckets per k_closs block
#define FXS2  268435456.0f        // 2^28 fixed-point scale for sum(v-center)
#define FXSI2 (1.0/268435456.0)

// blocks 0-63: pack masks to bits (byte-wise, R10-proven layout).
// blocks 64-575: (slice s, channel-octet g) masked J minmax partials.
__global__ __launch_bounds__(512) void k_prep(
    const float* __restrict__ J, const int* __restrict__ mI,
    const int* __restrict__ mJ, unsigned char* __restrict__ bI,
    unsigned char* __restrict__ bJ, unsigned* __restrict__ mnp,
    unsigned* __restrict__ mxp, double* __restrict__ lossacc,
    unsigned* __restrict__ donecnt)
{
  const int bx = blockIdx.x, tid = threadIdx.x;
  __shared__ unsigned smn[8][8], smx[8][8];
  if(bx < 64){
    const int t = bx*512 + tid;                      // 32768 threads x 8 px
    const int4* a = (const int4*)mI + 2*t;
    int4 x0 = a[0], x1 = a[1];
    unsigned b = (unsigned)((x0.x>0)|((x0.y>0)<<1)|((x0.z>0)<<2)|((x0.w>0)<<3)
               |((x1.x>0)<<4)|((x1.y>0)<<5)|((x1.z>0)<<6)|((x1.w>0)<<7));
    const int4* cm = (const int4*)mJ + 2*t;
    int4 y0 = cm[0], y1 = cm[1];
    unsigned d = (unsigned)((y0.x>0)|((y0.y>0)<<1)|((y0.z>0)<<2)|((y0.w>0)<<3)
               |((y1.x>0)<<4)|((y1.y>0)<<5)|((y1.z>0)<<6)|((y1.w>0)<<7));
    bI[t] = (unsigned char)b;
    bJ[t] = (unsigned char)d;
    if(bx == 0 && tid == 0){ *lossacc = 0.0; *donecnt = 0u; }
    return;
  }
  const int m = bx - 64, s = m >> 3, g = m & 7;      // slice, channel-octet
  const int wid = tid >> 6, lane = tid & 63;
  const int4* mj4 = (const int4*)mJ + s*(MMPIX/4);   // mask nibbles, in regs,
  int4 y0 = mj4[tid], y1 = mj4[512 + tid];           // reused for 8 channels
  unsigned b40 = (unsigned)((y0.x>0)|((y0.y>0)<<1)|((y0.z>0)<<2)|((y0.w>0)<<3));
  unsigned b41 = (unsigned)((y1.x>0)|((y1.y>0)<<1)|((y1.z>0)<<2)|((y1.w>0)<<3));
  #pragma unroll
  for(int ch = 0; ch < 8; ch++){
    const int c = g*8 + ch;
    const float4* Jc = (const float4*)(J + (size_t)c*HWN + (size_t)s*MMPIX);
    float4 v0 = Jc[tid], v1 = Jc[512 + tid];
    unsigned mn = 0x7F800000u, mx = 0u;              // J in [0,1): uint-monotone
    if(b40&1u){unsigned u=__float_as_uint(v0.x); mn=min(mn,u); mx=max(mx,u);}
    if(b40&2u){unsigned u=__float_as_uint(v0.y); mn=min(mn,u); mx=max(mx,u);}
    if(b40&4u){unsigned u=__float_as_uint(v0.z); mn=min(mn,u); mx=max(mx,u);}
    if(b40&8u){unsigned u=__float_as_uint(v0.w); mn=min(mn,u); mx=max(mx,u);}
    if(b41&1u){unsigned u=__float_as_uint(v1.x); mn=min(mn,u); mx=max(mx,u);}
    if(b41&2u){unsigned u=__float_as_uint(v1.y); mn=min(mn,u); mx=max(mx,u);}
    if(b41&4u){unsigned u=__float_as_uint(v1.z); mn=min(mn,u); mx=max(mx,u);}
    if(b41&8u){unsigned u=__float_as_uint(v1.w); mn=min(mn,u); mx=max(mx,u);}
    for(int o = 32; o > 0; o >>= 1){
      mn = min(mn, (unsigned)__shfl_down(mn, o, 64));
      mx = max(mx, (unsigned)__shfl_down(mx, o, 64));
    }
    if(lane == 0){ smn[wid][ch] = mn; smx[wid][ch] = mx; }
  }
  __syncthreads();
  if(tid < 8){                                       // ch = tid
    unsigned mn = 0x7F800000u, mx = 0u;
    for(int w = 0; w < 8; w++){ mn = min(mn, smn[w][tid]); mx = max(mx, smx[w][tid]); }
    mnp[(g*8 + tid)*MMS + s] = mn;
    mxp[(g*8 + tid)*MMS + s] = mx;
  }
}

__device__ __forceinline__ void px_i(float v, float& qacc, unsigned& ci,
                                     unsigned* buk){
  int k = (int)(v * (float)NBUK);                    // pow2 scale: exact, monotone
  if(k > NBUK-1) k = NBUK-1;
  float dv = v - ((float)k + 0.5f) * (1.0f/(float)NBUK);
  int fx = (int)rintf(dv * FXS2);                    // |fx| <= 16384
  atomicAdd(&buk[k], ((unsigned)fx << 12) + 1u);
  qacc += dv*dv;
  ci++;
}

// pass1 + J-histogram fused (minmax known from k_prep via boundary).
__global__ __launch_bounds__(PT, 2) void k_p1h(
    const float* __restrict__ I, const float* __restrict__ J,
    const unsigned* __restrict__ bIw, const unsigned* __restrict__ bJw,
    const unsigned* __restrict__ mnp, const unsigned* __restrict__ mxp,
    unsigned* __restrict__ pc, unsigned* __restrict__ qtot,
    unsigned* __restrict__ hisPart, unsigned* __restrict__ cp,
    double* __restrict__ qp)
{
  const int c = blockIdx.y, q = blockIdx.x, tid = threadIdx.x;
  const int bid = c*NBLK + q;
  const int wid = tid >> 6, lane = tid & 63;
  __shared__ unsigned buk[NBUK];                    // packed (fx<<12)+count
  __shared__ unsigned smbI[BPIX/32], smbJ[BPIX/32]; // 512 words each
  __shared__ unsigned h2[2][NB];                    // J-hist sub-hists
  __shared__ double   dred[PT/64];
  __shared__ unsigned uci[PT/64], ucj[PT/64];
  __shared__ float sh_mn, sh_den;
  for(int i = tid; i < NBUK; i += PT) buk[i] = 0u;
  smbI[tid] = bIw[q*512 + tid];                     // PT == 512 words
  smbJ[tid] = bJw[q*512 + tid];
  if(tid < NB){ h2[0][tid] = 0u; h2[1][tid] = 0u; }
  if(tid < MMS){                                    // channel minmax, 1 wave
    unsigned mn = mnp[c*MMS + tid];
    unsigned mx = mxp[c*MMS + tid];
    for(int o = 32; o > 0; o >>= 1){
      mn = min(mn, (unsigned)__shfl_down(mn, o, 64));
      mx = max(mx, (unsigned)__shfl_down(mx, o, 64));
    }
    if(tid == 0){
      float mnv = __uint_as_float(mn);
      sh_mn  = mnv;
      sh_den = fmaxf((__uint_as_float(mx) - mnv) / (float)NB, 1e-12f);
    }
  }
  __syncthreads();

  const float4* Ic = (const float4*)(I + (size_t)c*HWN + (size_t)q*BPIX);
  const float4* Jc = (const float4*)(J + (size_t)c*HWN + (size_t)q*BPIX);
  const float mnv = sh_mn, den = sh_den;
  float qacc = 0.0f;
  unsigned ci = 0, cj = 0;
  const int nsh = (tid & 7) * 4;
  const int bw  = tid >> 3;
  unsigned* hh = h2[wid & 1];

  float4 pi[2], pj[2];                              // 2-deep reg pipeline (R12)
  pi[0] = Ic[tid]; pj[0] = Jc[tid];
  #pragma unroll
  for(int g = 0; g < 8; g++){
    const int cur = g & 1, nxt = cur ^ 1;
    if(g < 7){ pi[nxt] = Ic[(g+1)*PT + tid]; pj[nxt] = Jc[(g+1)*PT + tid]; }
    const unsigned bitsI = (smbI[g*64 + bw] >> nsh) & 0xFu;
    const unsigned bitsJ = (smbJ[g*64 + bw] >> nsh) & 0xFu;
    float4 vi = pi[cur], vj = pj[cur];
    if(bitsI & 1u) px_i(vi.x, qacc, ci, buk);
    if(bitsI & 2u) px_i(vi.y, qacc, ci, buk);
    if(bitsI & 4u) px_i(vi.z, qacc, ci, buk);
    if(bitsI & 8u) px_i(vi.w, qacc, ci, buk);
    if(bitsJ & 1u){ float bf = floorf((vj.x - mnv)/den);  // ref rounding
      bf = fminf(fmaxf(bf,0.0f),255.0f); atomicAdd(&hh[(int)bf],1u); cj++; }
    if(bitsJ & 2u){ float bf = floorf((vj.y - mnv)/den);
      bf = fminf(fmaxf(bf,0.0f),255.0f); atomicAdd(&hh[(int)bf],1u); cj++; }
    if(bitsJ & 4u){ float bf = floorf((vj.z - mnv)/den);
      bf = fminf(fmaxf(bf,0.0f),255.0f); atomicAdd(&hh[(int)bf],1u); cj++; }
    if(bitsJ & 8u){ float bf = floorf((vj.w - mnv)/den);
      bf = fminf(fmaxf(bf,0.0f),255.0f); atomicAdd(&hh[(int)bf],1u); cj++; }
  }
  __syncthreads();                                   // LDS atomics complete
  { unsigned* pcb = pc + (size_t)bid * NBUK;
    for(int i = tid; i < NBUK; i += PT) pcb[i] = buk[i]; }
  if(tid < NB) hisPart[(size_t)bid*NB + tid] = h2[0][tid] + h2[1][tid];

  // qtot: 32 groups of 256 buckets; 16-thread shfl reduce (integer-exact)
  { unsigned csum = 0;
    #pragma unroll
    for(int j = 0; j < 16; j++) csum += buk[tid*16 + j] & 0xFFFu;
    csum += __shfl_down(csum, 8, 64);
    csum += __shfl_down(csum, 4, 64);
    csum += __shfl_down(csum, 2, 64);
    csum += __shfl_down(csum, 1, 64);
    if((tid & 15) == 0) qtot[bid*32 + (tid >> 4)] = csum;
  }

  double qd = (double)qacc;
  for(int o = 32; o > 0; o >>= 1){
    qd += __shfl_down(qd, o, 64);
    ci += __shfl_down(ci, o, 64);
    cj += __shfl_down(cj, o, 64);
  }
  if(lane == 0){ dred[wid] = qd; uci[wid] = ci; ucj[wid] = cj; }
  __syncthreads();
  if(tid == 0){
    double t = 0.0; unsigned aci = 0, acj = 0;
    for(int w = 0; w < PT/64; w++){ t += dred[w]; aci += uci[w]; acj += ucj[w]; }
    qp[bid] = t;
    if(c == 0){ cp[2*q] = aci; cp[2*q+1] = acj; }
  }
}

// Per-channel tables ONCE: hisPart reduce, cumsum (ref rounding),
// qtot group prefix, minmax, ratio. 64 blocks x 256 threads.
__global__ __launch_bounds__(256) void k_tab(
    const unsigned* __restrict__ hisPart, const unsigned* __restrict__ qtot,
    const unsigned* __restrict__ mnp, const unsigned* __restrict__ mxp,
    const unsigned* __restrict__ cp,
    float* __restrict__ chs, float* __restrict__ ccs,
    float* __restrict__ cmn, float* __restrict__ cst,
    unsigned* __restrict__ colpre)
{
  const int c = blockIdx.x, tid = threadIdx.x;
  __shared__ unsigned hsum[NB], colsum[32];
  __shared__ float hsf[NB], csf[NB];
  { unsigned hr = 0u;                                // hisPart reduce
    #pragma unroll
    for(int xb = 0; xb < NBLK; xb++) hr += hisPart[(size_t)(c*NBLK + xb)*NB + tid];
    hsum[tid] = hr; }
  if(tid < 32){                                      // qtot column sums
    unsigned s = 0;
    #pragma unroll
    for(int sl = 0; sl < NBLK; sl++) s += qtot[c*NBLK*32 + sl*32 + tid];
    colsum[tid] = s;
  }
  if(tid >= 64 && tid < 128){                        // minmax on wave 1
    const int l = tid - 64;
    unsigned mn = mnp[c*MMS + l], mx = mxp[c*MMS + l];
    for(int o = 32; o > 0; o >>= 1){
      mn = min(mn, (unsigned)__shfl_down(mn, o, 64));
      mx = max(mx, (unsigned)__shfl_down(mx, o, 64));
    }
    if(l == 0){
      float mnv = __uint_as_float(mn);
      cmn[c] = mnv;
      cst[c] = (__uint_as_float(mx) - mnv) / (float)NB;
    }
  }
  __syncthreads();
  if(tid == 0){
    unsigned ciw = 0, cjw = 0;
    for(int qi = 0; qi < NBLK; qi++){ ciw += cp[2*qi]; cjw += cp[2*qi+1]; }
    float ratio = (float)ciw / (float)cjw;           // nI/nJ in f32, as in ref
    float cum = 0.0f;
    for(int b = 0; b < NB; b++){
      float hh = (float)hsum[b] * ratio;
      hsf[b] = hh;
      cum += hh;                                     // sequential f32 == ref rounding
      csf[b] = cum;
    }
    unsigned base = 0;
    for(int g = 0; g < 32; g++){ colpre[c*32 + g] = base; base += colsum[g]; }
  }
  __syncthreads();
  chs[c*NB + tid] = hsf[tid];                        // f32 bit-copies
  ccs[c*NB + tid] = csf[tid];
}

// Bucket work only: 16 blk/ch x 512 thr, 1 bucket/thread.
__global__ __launch_bounds__(512) void k_closs(
    const unsigned* __restrict__ pc, const float* __restrict__ chs,
    const float* __restrict__ ccs, const float* __restrict__ cmn,
    const float* __restrict__ cst, const unsigned* __restrict__ colpre,
    const double* __restrict__ qp,
    double* __restrict__ lossacc, unsigned* __restrict__ donecnt,
    float* __restrict__ out)
{
  const int c = blockIdx.y, qt = blockIdx.x, tid = threadIdx.x;
  const int wid = tid >> 6, lane = tid & 63;
  __shared__ float cs[NB], hs[NB];
  __shared__ unsigned wsum[8];
  __shared__ double red2[8];
  if(tid < NB){ cs[tid] = ccs[c*NB + tid]; hs[tid] = chs[c*NB + tid]; }
  const float  mnvf = cmn[c], stepf = cst[c];
  const unsigned base = colpre[c*32 + qt*2];         // block = groups 2qt,2qt+1

  // pc reduce: bucket = qt*CBUK + tid; 4-way unrolled accumulators
  unsigned kk0=0, kk1=0, kk2=0, kk3=0;
  long long ss0=0, ss1=0, ss2=0, ss3=0;
  #pragma unroll
  for(int sl = 0; sl < NBLK; sl += 4){
    unsigned w0 = pc[(size_t)(c*NBLK + sl    )*NBUK + qt*CBUK + tid];
    unsigned w1 = pc[(size_t)(c*NBLK + sl + 1)*NBUK + qt*CBUK + tid];
    unsigned w2 = pc[(size_t)(c*NBLK + sl + 2)*NBUK + qt*CBUK + tid];
    unsigned w3 = pc[(size_t)(c*NBLK + sl + 3)*NBUK + qt*CBUK + tid];
    kk0 += w0 & 0xFFFu;  ss0 += (int)w0 >> 12;
    kk1 += w1 & 0xFFFu;  ss1 += (int)w1 >> 12;
    kk2 += w2 & 0xFFFu;  ss2 += (int)w2 >> 12;
    kk3 += w3 & 0xFFFu;  ss3 += (int)w3 >> 12;
  }
  unsigned  kk = kk0 + kk1 + kk2 + kk3;              // integer-exact
  long long ss = ss0 + ss1 + ss2 + ss3;
  unsigned v = kk;                                   // wave inclusive scan
  for(int o = 1; o < 64; o <<= 1){
    unsigned t = __shfl_up(v, o, 64);
    if(lane >= o) v += t;
  }
  if(lane == 63) wsum[wid] = v;
  __syncthreads();                                   // also covers cs/hs stores
  unsigned wbase = 0;
  for(int w = 0; w < wid; w++) wbase += wsum[w];
  unsigned texcl = base + wbase + (v - kk);

  double mnvd = (double)mnvf, stepd = (double)stepf;

  float rf0 = (float)(texcl + 1u);                   // left-search start bin
  int lo = 0, hi = NB;
  while(lo < hi){ int mid = (lo + hi) >> 1; if(cs[mid] < rf0) lo = mid + 1; else hi = mid; }
  int bin = (lo > NB-1) ? NB-1 : lo;

  double acc = 0.0;
  if(kk){
    unsigned ra = texcl + 1u, rb = texcl + kk;
    double sval = 0.0;
    while(ra <= rb){
      while(bin < NB-1 && cs[bin] < (float)ra) bin++;
      float csb = cs[bin], hsb = hs[bin];
      unsigned re = (bin == NB-1) ? rb : min(rb, (unsigned)floorf(csb));
      double lovd = (double)csb - (double)hsb;
      double den2 = fmax((double)hsb, 1e-12);
      double ra_d = (double)ra, re_d = (double)re, nn = (double)(re - ra + 1u);
      double rta = (ra_d - lovd)/den2, rtb = (re_d - lovd)/den2;
      if(hsb > 0.0f && rta >= 0.0 && rtb <= 1.0){
        double sumr = 0.5*(ra_d + re_d)*nn;          // arithmetic series of ranks
        sval += nn*(mnvd + (double)bin*stepd) + stepd*(sumr - nn*lovd)/den2;
      } else {                                       // exact per-rank f32 fallback
        for(unsigned rr = ra; rr <= re; rr++){
          float rf = (float)rr;
          float lov = csb - hsb;
          float rt = (rf - lov) / fmaxf(hsb, 1e-12f);
          rt = fminf(fmaxf(rt, 0.0f), 1.0f);
          sval += (double)(mnvf + ((float)bin + rt)*stepf);
        }
      }
      ra = re + 1u;
    }
    double kb   = (double)kk;
    double cb   = ((double)(qt*CBUK + tid) + 0.5) * (1.0/(double)NBUK);
    double vbar = sval/kb - cb;                      // mean(val) - bucket center
    double S    = (double)ss * FXSI2;                // sum(v - center)
    acc = kb*vbar*vbar - 2.0*vbar*S;
  }
  if(qt == 0 && tid == 0){                           // Q_c once per channel
    double qsum = 0.0;
    for(int qi = 0; qi < NBLK; qi++) qsum += qp[c*NBLK + qi];
    acc += qsum;
  }
  for(int o = 32; o > 0; o >>= 1) acc += __shfl_down(acc, o, 64);
  if(lane == 0) red2[wid] = acc;
  __syncthreads();
  if(tid == 0){
    double t = 0.0;
    for(int w = 0; w < 8; w++) t += red2[w];
    atomicAdd(lossacc, t);
    __threadfence();
    unsigned old = atomicAdd(donecnt, 1u);
    if(old == (unsigned)(CN*CLB - 1)){               // last block finalizes
      double tot = atomicAdd(lossacc, 0.0);          // coherent read
      out[0] = (float)(tot * (100.0 / (double)((size_t)CN * HWN)));
    }
  }
}

extern "C" void kernel_launch(void* const* d_in, const int* in_sizes, int n_in,
                              void* d_out, int out_size, void* d_ws, size_t ws_size,
                              hipStream_t stream){
  const float* I  = (const float*)d_in[0];
  const float* J  = (const float*)d_in[1];
  const int*   mI = (const int*)d_in[2];
  const int*   mJ = (const int*)d_in[3];
  float* out = (float*)d_out;

  char* base = (char*)d_ws;
  size_t pcB = (size_t)CN * NBLK * NBUK * sizeof(unsigned);      // 32 MB
  unsigned* pc      = (unsigned*)base;
  char* p = base + pcB;
  double*   qp      = (double*)p;   p += (size_t)CN*NBLK*sizeof(double);
  double*   lossacc = (double*)p;   p += sizeof(double);
  unsigned* hisPart = (unsigned*)p; p += (size_t)CN*NBLK*NB*sizeof(unsigned);
  unsigned* qtot    = (unsigned*)p; p += (size_t)CN*NBLK*32*sizeof(unsigned);
  unsigned* mnp     = (unsigned*)p; p += (size_t)CN*MMS*sizeof(unsigned);
  unsigned* mxp     = (unsigned*)p; p += (size_t)CN*MMS*sizeof(unsigned);
  unsigned* cp      = (unsigned*)p; p += 2*NBLK*sizeof(unsigned);
  float*    chs     = (float*)p;    p += (size_t)CN*NB*sizeof(float);
  float*    ccs     = (float*)p;    p += (size_t)CN*NB*sizeof(float);
  float*    cmn     = (float*)p;    p += CN*sizeof(float);
  float*    cst     = (float*)p;    p += CN*sizeof(float);
  unsigned* colpre  = (unsigned*)p; p += (size_t)CN*32*sizeof(unsigned);
  unsigned* donecnt = (unsigned*)p; p += sizeof(unsigned);
  size_t off = (size_t)(p - base); off = (off + 15) & ~(size_t)15;
  unsigned char* bIb = (unsigned char*)(base + off);             // 32 KB bits
  unsigned char* bJb = bIb + HWN/8;                              // 32 KB bits

  k_prep<<<576, 512, 0, stream>>>(J, mI, mJ, bIb, bJb, mnp, mxp,
                                  lossacc, donecnt);
  k_p1h<<<dim3(NBLK, CN), PT, 0, stream>>>(I, J, (const unsigned*)bIb,
                                           (const unsigned*)bJb, mnp, mxp,
                                           pc, qtot, hisPart, cp, qp);
  k_tab<<<CN, 256, 0, stream>>>(hisPart, qtot, mnp, mxp, cp,
                                chs, ccs, cmn, cst, colpre);
  k_closs<<<dim3(CLB, CN), 512, 0, stream>>>(pc, chs, ccs, cmn, cst, colpre,
                                             qp, lossacc, donecnt, out);
}